// Round 3
// baseline (642.424 us; speedup 1.0000x reference)
//
#include <hip/hip_runtime.h>
#include <hip/hip_bf16.h>
#include <stdint.h>

typedef short short8  __attribute__((ext_vector_type(8)));
typedef float f32x4   __attribute__((ext_vector_type(4)));
typedef float f32x16  __attribute__((ext_vector_type(16)));

typedef __attribute__((address_space(1))) uint32_t u32_g;
typedef __attribute__((address_space(3))) uint32_t u32_l;

#define BM 128
#define BN 128
#define BK 64

// async global->LDS, 16B per lane; LDS dest = wave-uniform base + lane*16.
__device__ __forceinline__ void gld_lds16(const void* g, const void* l) {
  __builtin_amdgcn_global_load_lds((u32_g*)(uintptr_t)g, (u32_l*)(uintptr_t)l, 16, 0, 0);
}

// ---------------------------------------------------------------------------
// Hidden-layer GEMM, 32x32x16 MFMA:
//   C[M,2048] = leakyrelu(A[M,K](bf16) @ BT[N,K](bf16)^T + bias)
// C/D layout (m74/m101): col = lane&31, row = (reg&3) + 8*(reg>>2) + 4*(lane>>5)
// -> one store instruction spans 32 lanes x 2B = 64B aligned segment (no RMW).
// ---------------------------------------------------------------------------
__global__ __launch_bounds__(256) void gemm32_k(
    const __hip_bfloat16* __restrict__ A,
    const __hip_bfloat16* __restrict__ BT,
    const float* __restrict__ bias,
    __hip_bfloat16* __restrict__ C,
    int K)
{
  __shared__ __attribute__((aligned(16))) __hip_bfloat16 As[BM * BK];
  __shared__ __attribute__((aligned(16))) __hip_bfloat16 Bs[BN * BK];

  const int tid  = threadIdx.x;
  const int lane = tid & 63;
  const int l31  = lane & 31;
  const int half = lane >> 5;
  const int wave = tid >> 6;
  const int wm   = (wave >> 1) << 6;
  const int wn   = (wave & 1) << 6;

  const int bm = blockIdx.x * BM;
  const int bn = blockIdx.y * BN;

  // Staging (same as R2): XOR chunk swizzle on the global side keeps LDS
  // wave-contiguous while fragment reads spread across banks.
  const __hip_bfloat16* ag[4];
  const __hip_bfloat16* bg[4];
  uint32_t lofs[4];
#pragma unroll
  for (int c = 0; c < 4; ++c) {
    int ci   = tid + 256 * c;
    int row  = ci >> 3;
    int chk  = ci & 7;
    int gchk = chk ^ (row & 7);
    ag[c]   = A  + (size_t)(bm + row) * K + gchk * 8;
    bg[c]   = BT + (size_t)(bn + row) * K + gchk * 8;
    lofs[c] = (uint32_t)ci * 16u;
  }

  f32x16 acc[2][2];
#pragma unroll
  for (int i = 0; i < 2; ++i)
#pragma unroll
    for (int j = 0; j < 2; ++j)
      acc[i][j] = (f32x16)(0.f);

  const int nk = K >> 6;
  for (int kt = 0; kt < nk; ++kt) {
#pragma unroll
    for (int c = 0; c < 4; ++c) {
      gld_lds16(ag[c], (const char*)As + lofs[c]);
      gld_lds16(bg[c], (const char*)Bs + lofs[c]);
      ag[c] += BK;
      bg[c] += BK;
    }
    __syncthreads();
#pragma unroll
    for (int kk = 0; kk < 4; ++kk) {        // 4 k-steps of 16
      short8 af[2], bf[2];
      const int cf = kk * 2 + half;         // 16B chunk: k = kk*16 + half*8
#pragma unroll
      for (int t = 0; t < 2; ++t) {
        int m  = wm + t * 32 + l31;
        af[t]  = *(const short8*)(As + m * BK + (cf ^ (m & 7)) * 8);
        int n  = wn + t * 32 + l31;
        bf[t]  = *(const short8*)(Bs + n * BK + (cf ^ (n & 7)) * 8);
      }
#pragma unroll
      for (int ti = 0; ti < 2; ++ti)
#pragma unroll
        for (int tj = 0; tj < 2; ++tj)
          acc[ti][tj] = __builtin_amdgcn_mfma_f32_32x32x16_bf16(af[ti], bf[tj], acc[ti][tj], 0, 0, 0);
    }
    __syncthreads();
  }

  // Epilogue: 64B-aligned sector-clean bf16 stores.
#pragma unroll
  for (int tj = 0; tj < 2; ++tj) {
    int   n  = bn + wn + tj * 32 + l31;
    float bv = bias[n];
#pragma unroll
    for (int ti = 0; ti < 2; ++ti) {
      int base = bm + wm + ti * 32 + 4 * half;
#pragma unroll
      for (int reg = 0; reg < 16; ++reg) {
        int m   = base + (reg & 3) + 8 * (reg >> 2);
        float v = acc[ti][tj][reg] + bv;
        v = (v > 0.f) ? v : 0.01f * v;
        C[(size_t)m * 2048 + n] = __float2bfloat16(v);
      }
    }
  }
}

// ---------------------------------------------------------------------------
// Final GEMM (16x16x32, proven path): y = A @ W3T^T + b3, diag-abs +
// triangle scatter as fp32: out[(r*64+c)*8192 + m], 16B f32x4 stores
// (4 quads -> 64B aligned segments).
// ---------------------------------------------------------------------------
__global__ __launch_bounds__(256) void gemm16f_k(
    const __hip_bfloat16* __restrict__ A,
    const __hip_bfloat16* __restrict__ BT,
    const float* __restrict__ bias,
    float* __restrict__ Cf,
    const int* __restrict__ tbl,
    int K, int Nreal)
{
  __shared__ __attribute__((aligned(16))) __hip_bfloat16 As[BM * BK];
  __shared__ __attribute__((aligned(16))) __hip_bfloat16 Bs[BN * BK];

  const int tid  = threadIdx.x;
  const int lane = tid & 63;
  const int l15  = lane & 15;
  const int quad = lane >> 4;
  const int wave = tid >> 6;
  const int wm   = (wave >> 1) << 6;
  const int wn   = (wave & 1) << 6;

  const int bm = blockIdx.x * BM;
  const int bn = blockIdx.y * BN;

  const __hip_bfloat16* ag[4];
  const __hip_bfloat16* bg[4];
  uint32_t lofs[4];
#pragma unroll
  for (int c = 0; c < 4; ++c) {
    int ci   = tid + 256 * c;
    int row  = ci >> 3;
    int chk  = ci & 7;
    int gchk = chk ^ (row & 7);
    ag[c]   = A  + (size_t)(bm + row) * K + gchk * 8;
    bg[c]   = BT + (size_t)(bn + row) * K + gchk * 8;
    lofs[c] = (uint32_t)ci * 16u;
  }

  f32x4 acc[4][4];
#pragma unroll
  for (int i = 0; i < 4; ++i)
#pragma unroll
    for (int j = 0; j < 4; ++j)
      acc[i][j] = (f32x4){0.f, 0.f, 0.f, 0.f};

  const int nk = K >> 6;
  for (int kt = 0; kt < nk; ++kt) {
#pragma unroll
    for (int c = 0; c < 4; ++c) {
      gld_lds16(ag[c], (const char*)As + lofs[c]);
      gld_lds16(bg[c], (const char*)Bs + lofs[c]);
      ag[c] += BK;
      bg[c] += BK;
    }
    __syncthreads();
#pragma unroll
    for (int ks = 0; ks < 2; ++ks) {
      short8 af[4], bf[4];
      const int cf = ks * 4 + quad;
#pragma unroll
      for (int i = 0; i < 4; ++i) {
        int m  = wm + i * 16 + l15;
        af[i]  = *(const short8*)(As + m * BK + ((cf ^ (m & 7)) * 8));
      }
#pragma unroll
      for (int j = 0; j < 4; ++j) {
        int n  = wn + j * 16 + l15;
        bf[j]  = *(const short8*)(Bs + n * BK + ((cf ^ (n & 7)) * 8));
      }
#pragma unroll
      for (int i = 0; i < 4; ++i)
#pragma unroll
        for (int j = 0; j < 4; ++j)
          acc[i][j] = __builtin_amdgcn_mfma_f32_16x16x32_bf16(af[i], bf[j], acc[i][j], 0, 0, 0);
    }
    __syncthreads();
  }

#pragma unroll
  for (int j = 0; j < 4; ++j) {
    int n = bn + wn + j * 16 + l15;
    if (n < Nreal) {
      float bv   = bias[n];
      int  code  = tbl[n];
      int  dst   = code & 4095;
      bool diag  = (code & 4096) != 0;
#pragma unroll
      for (int i = 0; i < 4; ++i) {
        int m0 = bm + wm + i * 16 + quad * 4;
        f32x4 pk;
#pragma unroll
        for (int r = 0; r < 4; ++r) {
          float v = acc[i][j][r] + bv;
          if (diag) v = fabsf(v);
          pk[r] = v;
        }
        *reinterpret_cast<f32x4*>(Cf + (size_t)dst * 8192 + m0) = pk;
      }
    }
  }
}

// ---------------------------------------------------------------------------
// Weight transpose + fp32->bf16: in[K,N](f32) -> out[NP,K](bf16)
// ---------------------------------------------------------------------------
__global__ void transpose_k(const float* __restrict__ in,
                            __hip_bfloat16* __restrict__ out,
                            int K, int N)
{
  __shared__ __hip_bfloat16 t[32][33];
  const int n0 = blockIdx.x * 32;
  const int k0 = blockIdx.y * 32;
  const int tx = threadIdx.x, ty = threadIdx.y;
  const __hip_bfloat16 zero = __float2bfloat16(0.f);
#pragma unroll
  for (int r = 0; r < 32; r += 8) {
    int k = k0 + ty + r, n = n0 + tx;
    t[ty + r][tx] = (n < N) ? __float2bfloat16(in[(size_t)k * N + n]) : zero;
  }
  __syncthreads();
#pragma unroll
  for (int r = 0; r < 32; r += 8) {
    int n = n0 + ty + r;
    out[(size_t)n * K + k0 + tx] = t[tx][ty + r];
  }
}

// fp32 -> bf16 elementwise (x), 4 per thread
__global__ void cvt_k(const float* __restrict__ in,
                      __hip_bfloat16* __restrict__ out, int n)
{
  int i = (blockIdx.x * 256 + threadIdx.x) * 4;
  if (i >= n) return;
  float4 v = *reinterpret_cast<const float4*>(in + i);
  union { unsigned short us[4]; uint2 v2; } pk;
  __hip_bfloat16 h;
  h = __float2bfloat16(v.x); pk.us[0] = *reinterpret_cast<unsigned short*>(&h);
  h = __float2bfloat16(v.y); pk.us[1] = *reinterpret_cast<unsigned short*>(&h);
  h = __float2bfloat16(v.z); pk.us[2] = *reinterpret_cast<unsigned short*>(&h);
  h = __float2bfloat16(v.w); pk.us[3] = *reinterpret_cast<unsigned short*>(&h);
  *reinterpret_cast<uint2*>(out + i) = pk.v2;
}

// l -> (r,c) scatter table. Diag flagged bit 12.
__global__ void table_k(int* __restrict__ tbl)
{
  int l = blockIdx.x * 64 + threadIdx.x;
  if (l >= 2080) return;
  int r = 0, s = 0;
  while (s + (64 - r) <= l) { s += 64 - r; ++r; }
  int c = 63 - (l - s);
  tbl[l] = (r * 64 + c) | ((r == c) ? 4096 : 0);
}

// Zero the lower triangle only: 2016 (r,c) pairs with c<r, 8192 floats each.
__global__ void zlo_k(float* __restrict__ out)
{
  int p = blockIdx.x;                       // 0..2015
  int r = (int)((1.0f + sqrtf(1.0f + 8.0f * (float)p)) * 0.5f);
  while (r * (r - 1) / 2 > p) --r;
  while ((r + 1) * r / 2 <= p) ++r;
  int c = p - r * (r - 1) / 2;              // c in [0, r)
  float* dst = out + (size_t)(r * 64 + c) * 8192;
  f32x4 z = (f32x4){0.f, 0.f, 0.f, 0.f};
#pragma unroll
  for (int i = 0; i < 8; ++i)
    *reinterpret_cast<f32x4*>(dst + i * 1024 + threadIdx.x * 4) = z;
}

extern "C" void kernel_launch(void* const* d_in, const int* in_sizes, int n_in,
                              void* d_out, int out_size, void* d_ws, size_t ws_size,
                              hipStream_t stream)
{
  const float* x   = (const float*)d_in[0];
  const float* W1  = (const float*)d_in[1];
  const float* b1  = (const float*)d_in[2];
  const float* W2  = (const float*)d_in[3];
  const float* b2  = (const float*)d_in[4];
  const float* W21 = (const float*)d_in[5];
  const float* b21 = (const float*)d_in[6];
  const float* W22 = (const float*)d_in[7];
  const float* b22 = (const float*)d_in[8];
  const float* W3  = (const float*)d_in[9];
  const float* b3  = (const float*)d_in[10];
  float* out = (float*)d_out;

  char* ws = (char*)d_ws;
  __hip_bfloat16* act0 = (__hip_bfloat16*)(ws);                         // 8192x2048 bf16
  __hip_bfloat16* act1 = (__hip_bfloat16*)(ws + ((size_t)32 << 20));    // 8192x2048 bf16
  __hip_bfloat16* xb   = act1;                                          // 8192x1024 (dead after GEMM1)
  __hip_bfloat16* W1T  = (__hip_bfloat16*)(ws + ((size_t)64 << 20));    // 2048x1024
  __hip_bfloat16* W2T  = (__hip_bfloat16*)(ws + ((size_t)68 << 20));    // 2048x2048
  __hip_bfloat16* W21T = (__hip_bfloat16*)(ws + ((size_t)76 << 20));    // 2048x2048
  __hip_bfloat16* W22T = (__hip_bfloat16*)(ws + ((size_t)84 << 20));    // 2048x2048
  __hip_bfloat16* W3T  = (__hip_bfloat16*)(ws + ((size_t)92 << 20));    // 2176x2048 (padded)
  int*            tbl  = (int*)(ws + ((size_t)101 << 20));              // 2080 ints

  table_k<<<33, 64, 0, stream>>>(tbl);
  zlo_k<<<2016, 256, 0, stream>>>(out);     // lower triangle -> 0

  cvt_k<<<8192, 256, 0, stream>>>(x, xb, 8192 * 1024);

  dim3 tb(32, 8);
  transpose_k<<<dim3(64, 32), tb, 0, stream>>>(W1,  W1T,  1024, 2048);
  transpose_k<<<dim3(64, 64), tb, 0, stream>>>(W2,  W2T,  2048, 2048);
  transpose_k<<<dim3(64, 64), tb, 0, stream>>>(W21, W21T, 2048, 2048);
  transpose_k<<<dim3(64, 64), tb, 0, stream>>>(W22, W22T, 2048, 2048);
  transpose_k<<<dim3(68, 64), tb, 0, stream>>>(W3,  W3T,  2048, 2080);

  gemm32_k<<<dim3(64, 16), 256, 0, stream>>>(xb,   W1T,  b1,  act0, 1024);
  gemm32_k<<<dim3(64, 16), 256, 0, stream>>>(act0, W2T,  b2,  act1, 2048);
  gemm32_k<<<dim3(64, 16), 256, 0, stream>>>(act1, W21T, b21, act0, 2048);
  gemm32_k<<<dim3(64, 16), 256, 0, stream>>>(act0, W22T, b22, act1, 2048);
  gemm16f_k<<<dim3(64, 17), 256, 0, stream>>>(act1, W3T, b3, out, tbl, 2048, 2080);
}

// Round 4
// 633.061 us; speedup vs baseline: 1.0148x; 1.0148x over previous
//
#include <hip/hip_runtime.h>
#include <hip/hip_bf16.h>
#include <stdint.h>

typedef short short8  __attribute__((ext_vector_type(8)));
typedef float f32x4   __attribute__((ext_vector_type(4)));
typedef float f32x16  __attribute__((ext_vector_type(16)));

typedef __attribute__((address_space(1))) uint32_t u32_g;
typedef __attribute__((address_space(3))) uint32_t u32_l;

#define BM 128
#define BN 128
#define BK 64

// async global->LDS, 16B per lane; LDS dest = wave-uniform base + lane*16.
__device__ __forceinline__ void gld_lds16(const void* g, const void* l) {
  __builtin_amdgcn_global_load_lds((u32_g*)(uintptr_t)g, (u32_l*)(uintptr_t)l, 16, 0, 0);
}

// ---------------------------------------------------------------------------
// Hidden-layer GEMM, 32x32x16 MFMA:
//   C[M,2048] = leakyrelu(A[M,K](bf16) @ BT[N,K](bf16)^T + bias)
// C/D layout (m74/m101): col = lane&31, row = (reg&3) + 8*(reg>>2) + 4*(lane>>5)
// -> one store spans 32 lanes x 2B = 64B aligned segment (no RMW; WRITE_SIZE
// measured 36.5 MB ~= ideal 33.5 MB in R3).
// ---------------------------------------------------------------------------
__global__ __launch_bounds__(256) void gemm32_k(
    const __hip_bfloat16* __restrict__ A,
    const __hip_bfloat16* __restrict__ BT,
    const float* __restrict__ bias,
    __hip_bfloat16* __restrict__ C,
    int K)
{
  __shared__ __attribute__((aligned(16))) __hip_bfloat16 As[BM * BK];
  __shared__ __attribute__((aligned(16))) __hip_bfloat16 Bs[BN * BK];

  const int tid  = threadIdx.x;
  const int lane = tid & 63;
  const int l31  = lane & 31;
  const int half = lane >> 5;
  const int wave = tid >> 6;
  const int wm   = (wave >> 1) << 6;
  const int wn   = (wave & 1) << 6;

  const int bm = blockIdx.x * BM;
  const int bn = blockIdx.y * BN;

  // Staging: XOR chunk swizzle on the global side keeps LDS wave-contiguous
  // (global_load_lds constraint) while fragment reads spread across banks.
  const __hip_bfloat16* ag[4];
  const __hip_bfloat16* bg[4];
  uint32_t lofs[4];
#pragma unroll
  for (int c = 0; c < 4; ++c) {
    int ci   = tid + 256 * c;
    int row  = ci >> 3;
    int chk  = ci & 7;
    int gchk = chk ^ (row & 7);
    ag[c]   = A  + (size_t)(bm + row) * K + gchk * 8;
    bg[c]   = BT + (size_t)(bn + row) * K + gchk * 8;
    lofs[c] = (uint32_t)ci * 16u;
  }

  f32x16 acc[2][2];
#pragma unroll
  for (int i = 0; i < 2; ++i)
#pragma unroll
    for (int j = 0; j < 2; ++j)
      acc[i][j] = (f32x16)(0.f);

  const int nk = K >> 6;
  for (int kt = 0; kt < nk; ++kt) {
#pragma unroll
    for (int c = 0; c < 4; ++c) {
      gld_lds16(ag[c], (const char*)As + lofs[c]);
      gld_lds16(bg[c], (const char*)Bs + lofs[c]);
      ag[c] += BK;
      bg[c] += BK;
    }
    __syncthreads();
#pragma unroll
    for (int kk = 0; kk < 4; ++kk) {        // 4 k-steps of 16
      short8 af[2], bf[2];
      const int cf = kk * 2 + half;         // 16B chunk: k = kk*16 + half*8
#pragma unroll
      for (int t = 0; t < 2; ++t) {
        int m  = wm + t * 32 + l31;
        af[t]  = *(const short8*)(As + m * BK + (cf ^ (m & 7)) * 8);
        int n  = wn + t * 32 + l31;
        bf[t]  = *(const short8*)(Bs + n * BK + (cf ^ (n & 7)) * 8);
      }
#pragma unroll
      for (int ti = 0; ti < 2; ++ti)
#pragma unroll
        for (int tj = 0; tj < 2; ++tj)
          acc[ti][tj] = __builtin_amdgcn_mfma_f32_32x32x16_bf16(af[ti], bf[tj], acc[ti][tj], 0, 0, 0);
    }
    __syncthreads();
  }

  // Epilogue: 64B-aligned sector-clean bf16 stores.
#pragma unroll
  for (int tj = 0; tj < 2; ++tj) {
    int   n  = bn + wn + tj * 32 + l31;
    float bv = bias[n];
#pragma unroll
    for (int ti = 0; ti < 2; ++ti) {
      int base = bm + wm + ti * 32 + 4 * half;
#pragma unroll
      for (int reg = 0; reg < 16; ++reg) {
        int m   = base + (reg & 3) + 8 * (reg >> 2);
        float v = acc[ti][tj][reg] + bv;
        v = (v > 0.f) ? v : 0.01f * v;
        C[(size_t)m * 2048 + n] = __float2bfloat16(v);
      }
    }
  }
}

// ---------------------------------------------------------------------------
// Final GEMM (16x16x32): y = A @ W3T^T + b3, diag-abs + triangle scatter as
// fp32: out[(r*64+c)*8192 + m], 16B f32x4 stores (64B aligned segments).
// ---------------------------------------------------------------------------
__global__ __launch_bounds__(256) void gemm16f_k(
    const __hip_bfloat16* __restrict__ A,
    const __hip_bfloat16* __restrict__ BT,
    const float* __restrict__ bias,
    float* __restrict__ Cf,
    const int* __restrict__ tbl,
    int K, int Nreal)
{
  __shared__ __attribute__((aligned(16))) __hip_bfloat16 As[BM * BK];
  __shared__ __attribute__((aligned(16))) __hip_bfloat16 Bs[BN * BK];

  const int tid  = threadIdx.x;
  const int lane = tid & 63;
  const int l15  = lane & 15;
  const int quad = lane >> 4;
  const int wave = tid >> 6;
  const int wm   = (wave >> 1) << 6;
  const int wn   = (wave & 1) << 6;

  const int bm = blockIdx.x * BM;
  const int bn = blockIdx.y * BN;

  const __hip_bfloat16* ag[4];
  const __hip_bfloat16* bg[4];
  uint32_t lofs[4];
#pragma unroll
  for (int c = 0; c < 4; ++c) {
    int ci   = tid + 256 * c;
    int row  = ci >> 3;
    int chk  = ci & 7;
    int gchk = chk ^ (row & 7);
    ag[c]   = A  + (size_t)(bm + row) * K + gchk * 8;
    bg[c]   = BT + (size_t)(bn + row) * K + gchk * 8;
    lofs[c] = (uint32_t)ci * 16u;
  }

  f32x4 acc[4][4];
#pragma unroll
  for (int i = 0; i < 4; ++i)
#pragma unroll
    for (int j = 0; j < 4; ++j)
      acc[i][j] = (f32x4){0.f, 0.f, 0.f, 0.f};

  const int nk = K >> 6;
  for (int kt = 0; kt < nk; ++kt) {
#pragma unroll
    for (int c = 0; c < 4; ++c) {
      gld_lds16(ag[c], (const char*)As + lofs[c]);
      gld_lds16(bg[c], (const char*)Bs + lofs[c]);
      ag[c] += BK;
      bg[c] += BK;
    }
    __syncthreads();
#pragma unroll
    for (int ks = 0; ks < 2; ++ks) {
      short8 af[4], bf[4];
      const int cf = ks * 4 + quad;
#pragma unroll
      for (int i = 0; i < 4; ++i) {
        int m  = wm + i * 16 + l15;
        af[i]  = *(const short8*)(As + m * BK + ((cf ^ (m & 7)) * 8));
      }
#pragma unroll
      for (int j = 0; j < 4; ++j) {
        int n  = wn + j * 16 + l15;
        bf[j]  = *(const short8*)(Bs + n * BK + ((cf ^ (n & 7)) * 8));
      }
#pragma unroll
      for (int i = 0; i < 4; ++i)
#pragma unroll
        for (int j = 0; j < 4; ++j)
          acc[i][j] = __builtin_amdgcn_mfma_f32_16x16x32_bf16(af[i], bf[j], acc[i][j], 0, 0, 0);
    }
    __syncthreads();
  }

#pragma unroll
  for (int j = 0; j < 4; ++j) {
    int n = bn + wn + j * 16 + l15;
    if (n < Nreal) {
      float bv   = bias[n];
      int  code  = tbl[n];
      int  dst   = code & 4095;
      bool diag  = (code & 4096) != 0;
#pragma unroll
      for (int i = 0; i < 4; ++i) {
        int m0 = bm + wm + i * 16 + quad * 4;
        f32x4 pk;
#pragma unroll
        for (int r = 0; r < 4; ++r) {
          float v = acc[i][j][r] + bv;
          if (diag) v = fabsf(v);
          pk[r] = v;
        }
        *reinterpret_cast<f32x4*>(Cf + (size_t)dst * 8192 + m0) = pk;
      }
    }
  }
}

// ---------------------------------------------------------------------------
// ONE prep dispatch: x-convert + 5 weight transposes (fp32->bf16, [K,N]->[N,K])
// + lower-triangle zero + scatter table. Flat grid, branch by block range
// (wave-uniform). Replaces 7 dispatches worth of ramp/drain.
// Block layout:
//   [0, 8192)          cvt x            (8192x1024, 4 elem/thread)
//   [8192, 26880)      transposes       (2048 + 3*4096 + 4352 blocks)
//   [26880, 28896)     zero lower tri   (2016 blocks)
//   [28896, 28905)     scatter table    (9 blocks)
// ---------------------------------------------------------------------------
__global__ __launch_bounds__(256) void prep_k(
    const float* __restrict__ x,   __hip_bfloat16* __restrict__ xb,
    const float* __restrict__ W1,  __hip_bfloat16* __restrict__ W1T,
    const float* __restrict__ W2,  __hip_bfloat16* __restrict__ W2T,
    const float* __restrict__ W21, __hip_bfloat16* __restrict__ W21T,
    const float* __restrict__ W22, __hip_bfloat16* __restrict__ W22T,
    const float* __restrict__ W3,  __hip_bfloat16* __restrict__ W3T,
    float* __restrict__ out, int* __restrict__ tbl)
{
  __shared__ __hip_bfloat16 t[32][33];
  const int tid = threadIdx.x;
  int bid = blockIdx.x;

  if (bid < 8192) {
    // ---- x fp32 -> bf16, 4/thread, coalesced ----
    int i = bid * 1024 + tid * 4;
    float4 v = *reinterpret_cast<const float4*>(x + i);
    union { unsigned short us[4]; uint2 v2; } pk;
    __hip_bfloat16 h;
    h = __float2bfloat16(v.x); pk.us[0] = *reinterpret_cast<unsigned short*>(&h);
    h = __float2bfloat16(v.y); pk.us[1] = *reinterpret_cast<unsigned short*>(&h);
    h = __float2bfloat16(v.z); pk.us[2] = *reinterpret_cast<unsigned short*>(&h);
    h = __float2bfloat16(v.w); pk.us[3] = *reinterpret_cast<unsigned short*>(&h);
    *reinterpret_cast<uint2*>(xb + i) = pk.v2;
    return;
  }
  bid -= 8192;

  if (bid < 18688) {
    // ---- weight transpose + convert: in[K,N](f32) -> out[n][k](bf16) ----
    const float* src; __hip_bfloat16* dst; int K, N, nbx, b;
    if (bid < 2048)       { src = W1;  dst = W1T;  K = 1024; N = 2048; nbx = 64; b = bid;         }
    else if (bid < 6144)  { src = W2;  dst = W2T;  K = 2048; N = 2048; nbx = 64; b = bid - 2048;  }
    else if (bid < 10240) { src = W21; dst = W21T; K = 2048; N = 2048; nbx = 64; b = bid - 6144;  }
    else if (bid < 14336) { src = W22; dst = W22T; K = 2048; N = 2048; nbx = 64; b = bid - 10240; }
    else                  { src = W3;  dst = W3T;  K = 2048; N = 2080; nbx = 68; b = bid - 14336; }
    const int bx = b % nbx, by = b / nbx;
    const int n0 = bx * 32, k0 = by * 32;
    const int tx = tid & 31, ty = tid >> 5;
    const __hip_bfloat16 zero = __float2bfloat16(0.f);
#pragma unroll
    for (int r = 0; r < 32; r += 8) {
      int k = k0 + ty + r, n = n0 + tx;
      t[ty + r][tx] = (n < N) ? __float2bfloat16(src[(size_t)k * N + n]) : zero;
    }
    __syncthreads();
#pragma unroll
    for (int r = 0; r < 32; r += 8) {
      int n = n0 + ty + r;
      dst[(size_t)n * K + k0 + tx] = t[tx][ty + r];  // rows n >= N get zeros (W3T pad)
    }
    return;
  }
  bid -= 18688;

  if (bid < 2016) {
    // ---- zero the lower triangle: (r,c) with c<r, 8192 floats each ----
    int p = bid;
    int r = (int)((1.0f + sqrtf(1.0f + 8.0f * (float)p)) * 0.5f);
    while (r * (r - 1) / 2 > p) --r;
    while ((r + 1) * r / 2 <= p) ++r;
    int c = p - r * (r - 1) / 2;
    float* dstp = out + (size_t)(r * 64 + c) * 8192;
    f32x4 z = (f32x4){0.f, 0.f, 0.f, 0.f};
#pragma unroll
    for (int i = 0; i < 8; ++i)
      *reinterpret_cast<f32x4*>(dstp + i * 1024 + tid * 4) = z;
    return;
  }
  bid -= 2016;

  // ---- l -> (r,c) scatter table; diag flagged bit 12 ----
  int l = bid * 256 + tid;
  if (l < 2080) {
    int r = 0, s = 0;
    while (s + (64 - r) <= l) { s += 64 - r; ++r; }
    int c = 63 - (l - s);
    tbl[l] = (r * 64 + c) | ((r == c) ? 4096 : 0);
  }
}

extern "C" void kernel_launch(void* const* d_in, const int* in_sizes, int n_in,
                              void* d_out, int out_size, void* d_ws, size_t ws_size,
                              hipStream_t stream)
{
  const float* x   = (const float*)d_in[0];
  const float* W1  = (const float*)d_in[1];
  const float* b1  = (const float*)d_in[2];
  const float* W2  = (const float*)d_in[3];
  const float* b2  = (const float*)d_in[4];
  const float* W21 = (const float*)d_in[5];
  const float* b21 = (const float*)d_in[6];
  const float* W22 = (const float*)d_in[7];
  const float* b22 = (const float*)d_in[8];
  const float* W3  = (const float*)d_in[9];
  const float* b3  = (const float*)d_in[10];
  float* out = (float*)d_out;

  char* ws = (char*)d_ws;
  __hip_bfloat16* act0 = (__hip_bfloat16*)(ws);                         // 8192x2048 bf16
  __hip_bfloat16* act1 = (__hip_bfloat16*)(ws + ((size_t)32 << 20));    // 8192x2048 bf16
  __hip_bfloat16* xb   = act1;                                          // 8192x1024 (dead after GEMM1)
  __hip_bfloat16* W1T  = (__hip_bfloat16*)(ws + ((size_t)64 << 20));    // 2048x1024
  __hip_bfloat16* W2T  = (__hip_bfloat16*)(ws + ((size_t)68 << 20));    // 2048x2048
  __hip_bfloat16* W21T = (__hip_bfloat16*)(ws + ((size_t)76 << 20));    // 2048x2048
  __hip_bfloat16* W22T = (__hip_bfloat16*)(ws + ((size_t)84 << 20));    // 2048x2048
  __hip_bfloat16* W3T  = (__hip_bfloat16*)(ws + ((size_t)92 << 20));    // 2176x2048 (padded)
  int*            tbl  = (int*)(ws + ((size_t)101 << 20));              // 2080 ints

  prep_k<<<28905, 256, 0, stream>>>(x, xb, W1, W1T, W2, W2T, W21, W21T,
                                    W22, W22T, W3, W3T, out, tbl);

  gemm32_k<<<dim3(64, 16), 256, 0, stream>>>(xb,   W1T,  b1,  act0, 1024);
  gemm32_k<<<dim3(64, 16), 256, 0, stream>>>(act0, W2T,  b2,  act1, 2048);
  gemm32_k<<<dim3(64, 16), 256, 0, stream>>>(act1, W21T, b21, act0, 2048);
  gemm32_k<<<dim3(64, 16), 256, 0, stream>>>(act0, W22T, b22, act1, 2048);
  gemm16f_k<<<dim3(64, 17), 256, 0, stream>>>(act1, W3T, b3, out, tbl, 2048, 2080);
}